// Round 1
// baseline (98.465 us; speedup 1.0000x reference)
//
#include <hip/hip_runtime.h>
#include <stdint.h>

typedef _Float16 f16x8 __attribute__((ext_vector_type(8)));
typedef float f32x4 __attribute__((ext_vector_type(4)));
typedef unsigned int u32x4 __attribute__((ext_vector_type(4)));

#define NT 8          // n-tiles (128/16)
#define NKT 5         // k-tiles (160/32): [W_hh | W_ih | bias | pad]
#define T_OBS 50
#define PRED 12

// ws layout (ushort == f16 bits):
//   enc frags: [t<8][kt<5][lane<64][j<8]   = 20480
//   dec frags: +20480
//   fc  frags: [kt<4][lane<64][j<8]        = 2048
#define DEC_OFF 20480
#define FC_OFF  40960
#define WS_ELEMS 43008

// kappa (physical A-column label) -> m (hidden-unit C/D-slot label)
// chosen so C/D slots feed B-frag slots with zero cross-lane movement:
// m0=k0, m1=k1, m2=k3, m3=k4, m4=k2, m5=k5, m6=k6
__device__ __forceinline__ int unperm(int k) {
  return (k & 3) | (((k >> 3) & 3) << 2) | (((k >> 2) & 1) << 4) | (k & 0x60);
}

__global__ void prep_kernel(const float* __restrict__ Wih_e, const float* __restrict__ Whh_e,
                            const float* __restrict__ bih_e, const float* __restrict__ bhh_e,
                            const float* __restrict__ Wih_d, const float* __restrict__ Whh_d,
                            const float* __restrict__ bih_d, const float* __restrict__ bhh_d,
                            const float* __restrict__ fcW,
                            unsigned short* __restrict__ ws) {
  int idx = blockIdx.x * 256 + threadIdx.x;
  if (idx >= WS_ELEMS) return;
  float val = 0.0f;
  if (idx < FC_OFF) {
    const bool enc = idx < DEC_OFF;
    const int e = enc ? idx : idx - DEC_OFF;
    const int j = e & 7;
    const int lane = (e >> 3) & 63;
    const int rem = e >> 9;            // t*5 + kt
    const int kt = rem % 5;
    const int t = rem / 5;
    const int n = 16 * t + (lane & 15);
    const int kappa = 32 * kt + ((lane >> 4) << 3) + j;
    const float* Wih = enc ? Wih_e : Wih_d;
    const float* Whh = enc ? Whh_e : Whh_d;
    const float* bih = enc ? bih_e : bih_d;
    const float* bhh = enc ? bhh_e : bhh_d;
    if (kappa < 128)       val = Whh[n * 128 + unperm(kappa)];
    else if (kappa < 131)  val = Wih[n * 3 + (kappa - 128)];
    else if (kappa == 131) val = bih[n] + bhh[n];
    // kappa >= 132 -> 0 (padding)
  } else {
    const int e = idx - FC_OFF;
    const int j = e & 7;
    const int lane = (e >> 3) & 63;
    const int kt = e >> 9;             // 0..3 (h part only; fc bias added in VALU)
    const int o = lane & 15;
    const int kappa = 32 * kt + ((lane >> 4) << 3) + j;
    if (o < 3) val = fcW[o * 128 + unperm(kappa)];
  }
  _Float16 h = (_Float16)val;
  ws[idx] = __builtin_bit_cast(unsigned short, h);
}

__device__ __forceinline__ float tanh_fast(float v) {
  // tanh(v) = 1 - 2/(1 + e^{2v});  e^{2v} = exp2(v * 2*log2(e))
  float e = __builtin_amdgcn_exp2f(v * 2.8853900817779268f);
  return 1.0f - 2.0f * __builtin_amdgcn_rcpf(1.0f + e);
}

__global__ __launch_bounds__(256, 2) void traj_kernel(
    const float* __restrict__ src, const unsigned short* __restrict__ ws,
    const float* __restrict__ fcb, float* __restrict__ out) {
  const int lane = (int)(threadIdx.x & 63u);
  const int wave = (int)(threadIdx.x >> 6u);
  const int seq = blockIdx.x * 64 + wave * 16 + (lane & 15);
  const int b = seq >> 6;      // /64 agents
  const int a = seq & 63;
  const bool act = (lane >> 4) == 0;   // hi==0 lanes own x/pred slots

  // ---- load encoder A-frags (shared by all waves; L2 broadcast) ----
  f16x8 A[NT * NKT];
  #pragma unroll
  for (int i = 0; i < NT * NKT; ++i) {
    u32x4 raw = *(const u32x4*)(ws + (size_t)(i * 64 + lane) * 8);
    A[i] = __builtin_bit_cast(f16x8, raw);
  }

  const float* xp = src + (size_t)b * (T_OBS * 192) + a * 3;
  float x0 = xp[0], x1 = xp[1], x2 = xp[2];

  f16x8 Bf[4];
  #pragma unroll
  for (int kt = 0; kt < 4; ++kt) {
    #pragma unroll
    for (int i = 0; i < 8; ++i) Bf[kt][i] = (_Float16)0.0f;  // h0 = 0
  }
  f16x8 xf;
  #pragma unroll
  for (int i = 0; i < 8; ++i) xf[i] = (_Float16)0.0f;
  if (act) { xf[0] = (_Float16)x0; xf[1] = (_Float16)x1; xf[2] = (_Float16)x2; xf[3] = (_Float16)1.0f; }

  // ---- encoder: 50 steps ----
  for (int s = 0; s < T_OBS; ++s) {
    const int t2 = (s < T_OBS - 1) ? s + 1 : s;   // clamp: after loop xf holds x[49] = dec_in0
    const float nx0 = xp[t2 * 192 + 0];
    const float nx1 = xp[t2 * 192 + 1];
    const float nx2 = xp[t2 * 192 + 2];

    f32x4 acc[NT];
    #pragma unroll
    for (int t = 0; t < NT; ++t) acc[t] = (f32x4){0.f, 0.f, 0.f, 0.f};

    #pragma unroll
    for (int kt = 0; kt < 4; ++kt) {
      #pragma unroll
      for (int t = 0; t < NT; ++t)
        acc[t] = __builtin_amdgcn_mfma_f32_16x16x32_f16(A[t * NKT + kt], Bf[kt], acc[t], 0, 0, 0);
    }
    #pragma unroll
    for (int t = 0; t < NT; ++t)
      acc[t] = __builtin_amdgcn_mfma_f32_16x16x32_f16(A[t * NKT + 4], xf, acc[t], 0, 0, 0);

    // tanh + repack straight into next step's B-frags (permutation makes this lane-local)
    #pragma unroll
    for (int kt = 0; kt < 4; ++kt) {
      #pragma unroll
      for (int q = 0; q < 4; ++q) {
        Bf[kt][q]     = (_Float16)tanh_fast(acc[2 * kt][q]);
        Bf[kt][4 + q] = (_Float16)tanh_fast(acc[2 * kt + 1][q]);
      }
    }
    x0 = nx0; x1 = nx1; x2 = nx2;
    #pragma unroll
    for (int i = 0; i < 8; ++i) xf[i] = (_Float16)0.0f;
    if (act) { xf[0] = (_Float16)x0; xf[1] = (_Float16)x1; xf[2] = (_Float16)x2; xf[3] = (_Float16)1.0f; }
  }

  // ---- swap in decoder weights ----
  #pragma unroll
  for (int i = 0; i < NT * NKT; ++i) {
    u32x4 raw = *(const u32x4*)(ws + DEC_OFF + (size_t)(i * 64 + lane) * 8);
    A[i] = __builtin_bit_cast(f16x8, raw);
  }
  f16x8 Afc[4];
  #pragma unroll
  for (int kt = 0; kt < 4; ++kt) {
    u32x4 raw = *(const u32x4*)(ws + FC_OFF + (size_t)(kt * 64 + lane) * 8);
    Afc[kt] = __builtin_bit_cast(f16x8, raw);
  }
  const float fb0 = fcb[0], fb1 = fcb[1], fb2 = fcb[2];

  float* op = out + (size_t)b * (PRED * 192) + a * 3;

  // ---- decoder: 12 autoregressive steps ----
  for (int p = 0; p < PRED; ++p) {
    f32x4 acc[NT];
    #pragma unroll
    for (int t = 0; t < NT; ++t) acc[t] = (f32x4){0.f, 0.f, 0.f, 0.f};

    #pragma unroll
    for (int kt = 0; kt < 4; ++kt) {
      #pragma unroll
      for (int t = 0; t < NT; ++t)
        acc[t] = __builtin_amdgcn_mfma_f32_16x16x32_f16(A[t * NKT + kt], Bf[kt], acc[t], 0, 0, 0);
    }
    #pragma unroll
    for (int t = 0; t < NT; ++t)
      acc[t] = __builtin_amdgcn_mfma_f32_16x16x32_f16(A[t * NKT + 4], xf, acc[t], 0, 0, 0);

    #pragma unroll
    for (int kt = 0; kt < 4; ++kt) {
      #pragma unroll
      for (int q = 0; q < 4; ++q) {
        Bf[kt][q]     = (_Float16)tanh_fast(acc[2 * kt][q]);
        Bf[kt][4 + q] = (_Float16)tanh_fast(acc[2 * kt + 1][q]);
      }
    }

    // fc head: one n-tile, K=128 (rows 3..15 of fc frags are zero)
    f32x4 pf = (f32x4){0.f, 0.f, 0.f, 0.f};
    #pragma unroll
    for (int kt = 0; kt < 4; ++kt)
      pf = __builtin_amdgcn_mfma_f32_16x16x32_f16(Afc[kt], Bf[kt], pf, 0, 0, 0);

    const float p0 = pf[0] + fb0;
    const float p1 = pf[1] + fb1;
    const float p2 = pf[2] + fb2;
    if (act) {
      op[p * 192 + 0] = p0;
      op[p * 192 + 1] = p1;
      op[p * 192 + 2] = p2;
    }
    // autoregressive feedback: pred becomes next input (already in the right lanes)
    #pragma unroll
    for (int i = 0; i < 8; ++i) xf[i] = (_Float16)0.0f;
    if (act) { xf[0] = (_Float16)p0; xf[1] = (_Float16)p1; xf[2] = (_Float16)p2; xf[3] = (_Float16)1.0f; }
  }
}

extern "C" void kernel_launch(void* const* d_in, const int* in_sizes, int n_in,
                              void* d_out, int out_size, void* d_ws, size_t ws_size,
                              hipStream_t stream) {
  const float* src   = (const float*)d_in[0];
  const float* Wih_e = (const float*)d_in[1];
  const float* Whh_e = (const float*)d_in[2];
  const float* bih_e = (const float*)d_in[3];
  const float* bhh_e = (const float*)d_in[4];
  const float* Wih_d = (const float*)d_in[5];
  const float* Whh_d = (const float*)d_in[6];
  const float* bih_d = (const float*)d_in[7];
  const float* bhh_d = (const float*)d_in[8];
  const float* fcW   = (const float*)d_in[9];
  const float* fcb   = (const float*)d_in[10];
  (void)in_sizes; (void)n_in; (void)out_size; (void)ws_size;

  unsigned short* ws = (unsigned short*)d_ws;

  prep_kernel<<<(WS_ELEMS + 255) / 256, 256, 0, stream>>>(
      Wih_e, Whh_e, bih_e, bhh_e, Wih_d, Whh_d, bih_d, bhh_d, fcW, ws);

  // 32768 sequences / 16 per wave / 4 waves per block = 512 blocks
  traj_kernel<<<512, 256, 0, stream>>>(src, ws, fcb, (float*)d_out);
}